// Round 3
// baseline (329.729 us; speedup 1.0000x reference)
//
#include <hip/hip_runtime.h>
#include <hip/hip_bf16.h>

// VQ-EMA forward for z:(32,64,32,32) fp32, 1024 codes of dim 64.
// Outputs (flat, fp32): z_q (2097152) | loss (1) | counts (1024)

#define N_ROWS   32768      // 32*32*32
#define N_CODES  1024
#define EDIM     64
#define ZQ_ELEMS 2097152    // 32*64*32*32

// ---------------- kernel 1: per-code squared norms -------------------------
__global__ void vq_enorm(const float* __restrict__ emb, float* __restrict__ enorm) {
    int c = blockIdx.x * 256 + threadIdx.x;
    if (c < N_CODES) {
        float s = 0.f;
        #pragma unroll
        for (int k = 0; k < EDIM; ++k) {
            float v = emb[(c << 6) + k];
            s = fmaf(v, v, s);
        }
        enorm[c] = s;
    }
}

// ---------------- kernel 2: distance + argmin + fused counts/sums ----------
// 512 blocks x 512 threads (8 waves). Block owns 64 consecutive rows.
// lane = row; each wave scans a 128-code range with embedding rows coming in
// through SCALAR loads (uniform address), z row held in 64 VGPRs.
__global__ __launch_bounds__(512, 2) void vq_dist(
        const float* __restrict__ z, const float* __restrict__ emb,
        const float* __restrict__ enorm,
        int* __restrict__ idx_out, float* __restrict__ counts,
        float* __restrict__ sums) {
    __shared__ float zs[64 * 65];      // zs[row][k], stride 65: conflict-free
    __shared__ float best_s[8 * 64];
    __shared__ int   bidx_s[8 * 64];
    __shared__ int   idx_sh[64];

    const int t    = threadIdx.x;      // 0..511
    const int lane = t & 63;
    const int wv   = t >> 6;           // 0..7
    const int r0   = blockIdx.x * 64;
    const int b    = r0 >> 10;
    const int hw0  = r0 & 1023;

    // ---- stage z into LDS (coalesced over hw); thread: row=lane, c=wv+8i --
    #pragma unroll
    for (int i = 0; i < 8; ++i) {
        const int c = wv + 8 * i;
        zs[lane * 65 + c] = z[((b * 64 + c) << 10) + hw0 + lane];
    }
    __syncthreads();

    // ---- z row into registers (conflict-free b32 reads, one-time) ----
    float zr[64];
    #pragma unroll
    for (int k = 0; k < EDIM; ++k) zr[k] = zs[lane * 65 + k];

    // ---- ||z||^2, sequential k (same order as previous passing round) ----
    float zn = 0.f;
    #pragma unroll
    for (int k = 0; k < EDIM; ++k) zn = fmaf(zr[k], zr[k], zn);

    // ---- scan this wave's 128 codes, 2-code ILP ----
    float best = INFINITY;
    int   bidx = 0;
    const int c0 = wv * 128;
    for (int c = c0; c < c0 + 128; c += 2) {
        const float* __restrict__ e0 = emb + (c << 6);   // uniform -> s_load
        float a0 = 0.f, a1 = 0.f;
        #pragma unroll
        for (int k = 0; k < EDIM; ++k) {
            a0 = fmaf(zr[k], e0[k], a0);
            a1 = fmaf(zr[k], e0[EDIM + k], a1);
        }
        const float s0 = (zn + enorm[c]) - 2.0f * a0;
        const float s1 = (zn + enorm[c + 1]) - 2.0f * a1;
        if (s0 < best) { best = s0; bidx = c; }
        if (s1 < best) { best = s1; bidx = c + 1; }
    }
    best_s[wv * 64 + lane] = best;
    bidx_s[wv * 64 + lane] = bidx;
    __syncthreads();

    // ---- cross-wave argmin (ranges ascending; strict < keeps lowest idx) --
    if (t < 64) {
        float bb = best_s[t];
        int   bi = bidx_s[t];
        #pragma unroll
        for (int w = 1; w < 8; ++w) {
            const float ob = best_s[w * 64 + t];
            const int   oi = bidx_s[w * 64 + t];
            if (ob < bb) { bb = ob; bi = oi; }
        }
        idx_out[r0 + t] = bi;
        idx_sh[t] = bi;
        atomicAdd(&counts[bi], 1.0f);
    }
    __syncthreads();

    // ---- fused segment-sum scatter (coalesced over k) ----
    #pragma unroll
    for (int i = 0; i < 8; ++i) {
        const int row = i * 8 + wv;
        atomicAdd(&sums[idx_sh[row] * 64 + lane], zs[row * 65 + lane]);
    }
}

// ---------------- kernel 3: EMA update -> new_embed; counts out; loss=0 ----
__global__ void vq_ema(const float* __restrict__ counts, const float* __restrict__ sums,
                       const float* __restrict__ cs, const float* __restrict__ csum,
                       float* __restrict__ new_embed, float* __restrict__ out_counts,
                       float* __restrict__ out_loss) {
    const int g = blockIdx.x * 256 + threadIdx.x;   // 0 .. 65535
    const int c = g >> 6, d = g & 63;
    const float cnt = counts[c];
    const float nsize = 0.99f * cs[c] + 0.01f * cnt;
    const float nsum  = 0.99f * csum[g] + 0.01f * sums[g];
    new_embed[g] = nsum / (nsize + 1e-5f);
    if (d == 0) out_counts[c] = cnt;
    if (g == 0) out_loss[0] = 0.f;
}

// ---------------- kernel 4: gather z_q, straight-through, loss -------------
__global__ __launch_bounds__(256) void vq_gather(
        const float* __restrict__ z, const int* __restrict__ idx,
        const float* __restrict__ new_embed,
        float* __restrict__ out_zq, float* __restrict__ out_loss) {
    __shared__ float red[4];
    const int t  = threadIdx.x;
    const int r0 = blockIdx.x * 256;
    const int b  = r0 >> 10;
    const int hw = (r0 & 1023) + t;
    const int myidx = idx[r0 + t];

    // load the full code row as 16 x float4 (fully unrolled -> registers)
    const float4* __restrict__ er = (const float4*)(new_embed + (myidx << 6));
    float4 e4[16];
    #pragma unroll
    for (int i = 0; i < 16; ++i) e4[i] = er[i];

    float lsum = 0.f;
    #pragma unroll
    for (int c = 0; c < 64; ++c) {
        const float e  = ((const float*)e4)[c];       // c constant after unroll
        const int  off = ((b * 64 + c) << 10) + hw;
        const float zv = z[off];
        const float diff = e - zv;                    // z_q - zp (fp32)
        out_zq[off] = zv + diff;                      // straight-through
        lsum = fmaf(diff, diff, lsum);
    }
    #pragma unroll
    for (int off = 32; off >= 1; off >>= 1) lsum += __shfl_down(lsum, off);
    if ((t & 63) == 0) red[t >> 6] = lsum;
    __syncthreads();
    if (t == 0) {
        const float s = red[0] + red[1] + red[2] + red[3];
        // BETA/count = 0.25 / 2^21 = 2^-23, exact in fp32
        atomicAdd(out_loss, s * (0.25f / 2097152.0f));
    }
}

// ---------------------------------------------------------------------------
extern "C" void kernel_launch(void* const* d_in, const int* in_sizes, int n_in,
                              void* d_out, int out_size, void* d_ws, size_t ws_size,
                              hipStream_t stream) {
    const float* z    = (const float*)d_in[0];   // (32,64,32,32)
    const float* emb  = (const float*)d_in[1];   // (1024,64)
    const float* cs   = (const float*)d_in[2];   // (1024,)
    const float* csum = (const float*)d_in[3];   // (1024,64)
    float* out = (float*)d_out;

    // ws layout
    int*   idx       = (int*)d_ws;                       // 32768 ints
    float* counts    = (float*)d_ws + 32768;             // 1024
    float* sums      = counts + 1024;                    // 65536
    float* enorm     = sums + 65536;                     // 1024
    float* new_embed = enorm + 1024;                     // 65536

    // zero the atomic accumulators (counts + sums)
    hipMemsetAsync(counts, 0, (1024 + 65536) * sizeof(float), stream);

    vq_enorm<<<4, 256, 0, stream>>>(emb, enorm);
    vq_dist<<<512, 512, 0, stream>>>(z, emb, enorm, idx, counts, sums);
    vq_ema<<<256, 256, 0, stream>>>(counts, sums, cs, csum, new_embed,
                                    out + ZQ_ELEMS + 1,   // counts out
                                    out + ZQ_ELEMS);      // loss out
    vq_gather<<<128, 256, 0, stream>>>(z, idx, new_embed, out, out + ZQ_ELEMS);
}

// Round 4
// 174.681 us; speedup vs baseline: 1.8876x; 1.8876x over previous
//
#include <hip/hip_runtime.h>
#include <hip/hip_bf16.h>

// VQ-EMA forward for z:(32,64,32,32) fp32, 1024 codes of dim 64.
// Outputs (flat, fp32): z_q (2097152) | loss (1) | counts (1024)

#define N_ROWS   32768      // 32*32*32
#define N_CODES  1024
#define EDIM     64
#define ZQ_ELEMS 2097152    // 32*64*32*32

// ---------------- kernel 0: zero counts+sums, compute enorm ----------------
// grid 264*256 = 67584 threads: [0,66560) zero counts|sums, rest do enorm.
__global__ void vq_prep(const float* __restrict__ emb, float* __restrict__ cs_zero,
                        float* __restrict__ enorm) {
    const int g = blockIdx.x * 256 + threadIdx.x;
    if (g < 66560) {
        cs_zero[g] = 0.f;
    } else {
        const int c = g - 66560;          // 0..1023
        const float4* __restrict__ e4 = (const float4*)(emb + (c << 6));
        float s = 0.f;
        #pragma unroll
        for (int i = 0; i < 16; ++i) {    // sequential k order (matches ref chain)
            const float4 v = e4[i];
            s = fmaf(v.x, v.x, s); s = fmaf(v.y, v.y, s);
            s = fmaf(v.z, v.z, s); s = fmaf(v.w, v.w, s);
        }
        enorm[c] = s;
    }
}

// ---------------- kernel 1: distance GEMM + per-half argmin ----------------
// grid (256 rowtiles, 2 code-halves) x 256 thr. Block: 128 rows x 512 codes.
// Thread tile 8x8 (rows ty+16rr, codes tx+16j), k via float4 along [r][k] LDS.
__global__ __launch_bounds__(256, 2) void vq_dist(
        const float* __restrict__ z, const float* __restrict__ emb,
        const float* __restrict__ enorm,
        float* __restrict__ half_score, int* __restrict__ half_idx) {
    __shared__ float zs[128 * 68];     // [row][k] pad 68 (17 float4)
    __shared__ float es[128 * 68];     // [code_local][k]
    __shared__ float zn_s[128];

    const int t    = threadIdx.x;
    const int tx   = t & 15, ty = t >> 4;
    const int r0   = blockIdx.x * 128;
    const int half = blockIdx.y;        // 0: codes 0-511, 1: codes 512-1023
    const int b    = r0 >> 10;
    const int hw0  = r0 & 1023;

    // ---- stage z (coalesced over hw; LDS [row][k]) ----
    #pragma unroll
    for (int i = 0; i < 32; ++i) {
        const int cell = i * 256 + t;
        const int row = cell & 127, c = cell >> 7;
        zs[row * 68 + c] = z[((b * 64 + c) << 10) + hw0 + row];
    }
    __syncthreads();

    // ---- per-row ||z||^2, sequential k ----
    if (t < 128) {
        const float4* z4 = (const float4*)zs + t * 17;
        float s = 0.f;
        #pragma unroll
        for (int g = 0; g < 16; ++g) {
            const float4 v = z4[g];
            s = fmaf(v.x, v.x, s); s = fmaf(v.y, v.y, s);
            s = fmaf(v.z, v.z, s); s = fmaf(v.w, v.w, s);
        }
        zn_s[t] = s;
    }
    __syncthreads();

    float znr[8];
    #pragma unroll
    for (int rr = 0; rr < 8; ++rr) znr[rr] = zn_s[ty + 16 * rr];

    float best[8]; int bidx[8];
    #pragma unroll
    for (int rr = 0; rr < 8; ++rr) { best[rr] = INFINITY; bidx[rr] = 0; }

    // ---- prefetch chunk 0 (128 codes = 2048 float4) ----
    const float4* __restrict__ eg = (const float4*)(emb + (half << 9) * 64);
    float4 pf[8];
    #pragma unroll
    for (int p = 0; p < 8; ++p) pf[p] = eg[p * 256 + t];

    for (int ch = 0; ch < 4; ++ch) {
        // write staged chunk to LDS (b128, conflict-free phases)
        #pragma unroll
        for (int p = 0; p < 8; ++p) {
            const int fid = p * 256 + t;
            ((float4*)es)[(fid >> 4) * 17 + (fid & 15)] = pf[p];
        }
        __syncthreads();
        if (ch < 3) {
            #pragma unroll
            for (int p = 0; p < 8; ++p) pf[p] = eg[(ch + 1) * 2048 + p * 256 + t];
        }
        // per-thread code norms for this chunk (precomputed, L2-hot)
        const int cbase = (half << 9) + (ch << 7);
        float enj[8];
        #pragma unroll
        for (int j = 0; j < 8; ++j) enj[j] = enorm[cbase + tx + 16 * j];

        // ---- 8x8 register tile, K=64 as 16 float4 steps (k ascending) ----
        float acc[8][8];
        #pragma unroll
        for (int rr = 0; rr < 8; ++rr)
            #pragma unroll
            for (int j = 0; j < 8; ++j) acc[rr][j] = 0.f;

        for (int g = 0; g < 16; ++g) {
            float4 zf[8], ef[8];
            #pragma unroll
            for (int rr = 0; rr < 8; ++rr) zf[rr] = ((const float4*)zs)[(ty + 16 * rr) * 17 + g];
            #pragma unroll
            for (int j = 0; j < 8; ++j)  ef[j] = ((const float4*)es)[(tx + 16 * j) * 17 + g];
            #pragma unroll
            for (int rr = 0; rr < 8; ++rr)
                #pragma unroll
                for (int j = 0; j < 8; ++j) {
                    float a = acc[rr][j];
                    a = fmaf(zf[rr].x, ef[j].x, a);
                    a = fmaf(zf[rr].y, ef[j].y, a);
                    a = fmaf(zf[rr].z, ef[j].z, a);
                    a = fmaf(zf[rr].w, ef[j].w, a);
                    acc[rr][j] = a;
                }
        }

        // ---- scores + running argmin (codes ascending within thread) ----
        #pragma unroll
        for (int rr = 0; rr < 8; ++rr)
            #pragma unroll
            for (int j = 0; j < 8; ++j) {
                const float s = (znr[rr] + enj[j]) - 2.0f * acc[rr][j];
                if (s < best[rr]) { best[rr] = s; bidx[rr] = cbase + tx + 16 * j; }
            }
        __syncthreads();   // protect es before next chunk's LDS write
    }

    // ---- reduce across the 16 tx lanes (tie -> lower code index) ----
    #pragma unroll
    for (int off = 1; off < 16; off <<= 1) {
        #pragma unroll
        for (int rr = 0; rr < 8; ++rr) {
            const float os = __shfl_xor(best[rr], off);
            const int   oi = __shfl_xor(bidx[rr], off);
            if (os < best[rr] || (os == best[rr] && oi < bidx[rr])) {
                best[rr] = os; bidx[rr] = oi;
            }
        }
    }
    if (tx == 0) {
        #pragma unroll
        for (int rr = 0; rr < 8; ++rr) {
            const int gr = r0 + ty + 16 * rr;
            half_score[half * N_ROWS + gr] = best[rr];
            half_idx  [half * N_ROWS + gr] = bidx[rr];
        }
    }
}

// ---------------- kernel 2: resolve argmin across halves + counts/sums ----
__global__ __launch_bounds__(256) void vq_resolve(
        const float* __restrict__ z,
        const float* __restrict__ half_score, const int* __restrict__ half_idx,
        int* __restrict__ idx_out, float* __restrict__ counts,
        float* __restrict__ sums) {
    __shared__ float zs[128 * 65];
    __shared__ int   idx_sh[128];
    const int t   = threadIdx.x;
    const int r0  = blockIdx.x * 128;
    const int b   = r0 >> 10;
    const int hw0 = r0 & 1023;

    #pragma unroll
    for (int i = 0; i < 32; ++i) {
        const int cell = i * 256 + t;
        const int row = cell & 127, c = cell >> 7;
        zs[row * 65 + c] = z[((b * 64 + c) << 10) + hw0 + row];
    }
    if (t < 128) {
        const int gr = r0 + t;
        const float s0 = half_score[gr], s1 = half_score[N_ROWS + gr];
        const int   i0 = half_idx[gr],   i1 = half_idx[N_ROWS + gr];
        const int   bi = (s1 < s0) ? i1 : i0;   // tie -> half 0 (lower codes)
        idx_out[gr] = bi;
        idx_sh[t] = bi;
        atomicAdd(&counts[bi], 1.0f);
    }
    __syncthreads();

    const int lane = t & 63, sub = t >> 6;
    #pragma unroll
    for (int i = 0; i < 32; ++i) {
        const int row = i * 4 + sub;
        atomicAdd(&sums[idx_sh[row] * 64 + lane], zs[row * 65 + lane]);
    }
}

// ---------------- kernel 3: EMA update -> new_embed; counts out; loss=0 ----
__global__ void vq_ema(const float* __restrict__ counts, const float* __restrict__ sums,
                       const float* __restrict__ cs, const float* __restrict__ csum,
                       float* __restrict__ new_embed, float* __restrict__ out_counts,
                       float* __restrict__ out_loss) {
    const int g = blockIdx.x * 256 + threadIdx.x;   // 0 .. 65535
    const int c = g >> 6, d = g & 63;
    const float cnt = counts[c];
    const float nsize = 0.99f * cs[c] + 0.01f * cnt;
    const float nsum  = 0.99f * csum[g] + 0.01f * sums[g];
    new_embed[g] = nsum / (nsize + 1e-5f);
    if (d == 0) out_counts[c] = cnt;
    if (g == 0) out_loss[0] = 0.f;
}

// ---------------- kernel 4: gather z_q, straight-through, loss -------------
__global__ __launch_bounds__(256) void vq_gather(
        const float* __restrict__ z, const int* __restrict__ idx,
        const float* __restrict__ new_embed,
        float* __restrict__ out_zq, float* __restrict__ out_loss) {
    __shared__ float red[4];
    const int t  = threadIdx.x;
    const int r0 = blockIdx.x * 256;
    const int b  = r0 >> 10;
    const int hw = (r0 & 1023) + t;
    const int myidx = idx[r0 + t];

    const float4* __restrict__ er = (const float4*)(new_embed + (myidx << 6));
    float4 e4[16];
    #pragma unroll
    for (int i = 0; i < 16; ++i) e4[i] = er[i];

    float lsum = 0.f;
    #pragma unroll
    for (int c = 0; c < 64; ++c) {
        const float e  = ((const float*)e4)[c];
        const int  off = ((b * 64 + c) << 10) + hw;
        const float zv = z[off];
        const float diff = e - zv;                    // z_q - zp (fp32)
        out_zq[off] = zv + diff;                      // straight-through
        lsum = fmaf(diff, diff, lsum);
    }
    #pragma unroll
    for (int off = 32; off >= 1; off >>= 1) lsum += __shfl_down(lsum, off);
    if ((t & 63) == 0) red[t >> 6] = lsum;
    __syncthreads();
    if (t == 0) {
        const float s = red[0] + red[1] + red[2] + red[3];
        atomicAdd(out_loss, s * (0.25f / 2097152.0f));   // BETA/2^21 exact
    }
}

// ---------------------------------------------------------------------------
extern "C" void kernel_launch(void* const* d_in, const int* in_sizes, int n_in,
                              void* d_out, int out_size, void* d_ws, size_t ws_size,
                              hipStream_t stream) {
    const float* z    = (const float*)d_in[0];   // (32,64,32,32)
    const float* emb  = (const float*)d_in[1];   // (1024,64)
    const float* cs   = (const float*)d_in[2];   // (1024,)
    const float* csum = (const float*)d_in[3];   // (1024,64)
    float* out = (float*)d_out;

    // ws layout
    int*   idx        = (int*)d_ws;                      // 32768 ints
    float* counts     = (float*)d_ws + 32768;            // 1024  (zeroed by prep)
    float* sums       = counts + 1024;                   // 65536 (zeroed by prep)
    float* enorm      = sums + 65536;                    // 1024
    float* new_embed  = enorm + 1024;                    // 65536
    float* half_score = new_embed + 65536;               // 2*32768
    int*   half_idx   = (int*)(half_score + 2 * 32768);  // 2*32768

    vq_prep<<<264, 256, 0, stream>>>(emb, counts, enorm);
    vq_dist<<<dim3(256, 2), 256, 0, stream>>>(z, emb, enorm, half_score, half_idx);
    vq_resolve<<<256, 256, 0, stream>>>(z, half_score, half_idx, idx, counts, sums);
    vq_ema<<<256, 256, 0, stream>>>(counts, sums, cs, csum, new_embed,
                                    out + ZQ_ELEMS + 1,   // counts out
                                    out + ZQ_ELEMS);      // loss out
    vq_gather<<<128, 256, 0, stream>>>(z, idx, new_embed, out, out + ZQ_ELEMS);
}

// Round 6
// 170.294 us; speedup vs baseline: 1.9362x; 1.0258x over previous
//
#include <hip/hip_runtime.h>
#include <hip/hip_bf16.h>

// VQ-EMA forward for z:(32,64,32,32) fp32, 1024 codes of dim 64.
// Outputs (flat, fp32): z_q (2097152) | loss (1) | counts (1024)

#define N_ROWS   32768      // 32*32*32
#define N_CODES  1024
#define EDIM     64
#define ZQ_ELEMS 2097152    // 32*64*32*32
#define NSPLIT   4          // privatized atomic copies

// ---------------- kernel 1: per-code squared norms -------------------------
__global__ void vq_enorm(const float* __restrict__ emb, float* __restrict__ enorm) {
    const int c = blockIdx.x * 256 + threadIdx.x;
    if (c < N_CODES) {
        const float4* __restrict__ e4 = (const float4*)(emb + (c << 6));
        float s = 0.f;
        #pragma unroll
        for (int i = 0; i < 16; ++i) {    // sequential k (matches ref chain)
            const float4 v = e4[i];
            s = fmaf(v.x, v.x, s); s = fmaf(v.y, v.y, s);
            s = fmaf(v.z, v.z, s); s = fmaf(v.w, v.w, s);
        }
        enorm[c] = s;
    }
}

// ---- fragment helpers (force static indexing after inline+unroll) ---------
__device__ __forceinline__ void ldfrag(float4 (&dst)[8], const float4* __restrict__ s4,
                                       int lane, int g) {
    #pragma unroll
    for (int r = 0; r < 8; ++r) dst[r] = s4[(lane + 16 * r) * 17 + g];
}
__device__ __forceinline__ void fma_tile(const float4 (&zf)[8], const float4 (&ef)[8],
                                         float (&acc)[8][8]) {
    #pragma unroll
    for (int rr = 0; rr < 8; ++rr)
        #pragma unroll
        for (int j = 0; j < 8; ++j) {
            float a = acc[rr][j];
            a = fmaf(zf[rr].x, ef[j].x, a);
            a = fmaf(zf[rr].y, ef[j].y, a);
            a = fmaf(zf[rr].z, ef[j].z, a);
            a = fmaf(zf[rr].w, ef[j].w, a);
            acc[rr][j] = a;
        }
}

// ---------------- kernel 2: distance GEMM + per-half argmin ----------------
// grid (256 rowtiles, 2 code-halves) x 256 thr. Block: 128 rows x 512 codes.
__global__ __launch_bounds__(256, 2) void vq_dist(
        const float* __restrict__ z, const float* __restrict__ emb,
        const float* __restrict__ enorm,
        float* __restrict__ half_score, int* __restrict__ half_idx) {
    __shared__ float zs[128 * 68];     // [row][k] pad 68 (17 float4)
    __shared__ float es[128 * 68];     // [code_local][k]
    __shared__ float zn_s[128];

    const int t    = threadIdx.x;
    const int tx   = t & 15, ty = t >> 4;
    const int r0   = blockIdx.x * 128;
    const int half = blockIdx.y;        // 0: codes 0-511, 1: codes 512-1023
    const int b    = r0 >> 10;
    const int hw0  = r0 & 1023;

    // ---- stage z (coalesced over hw; LDS [row][k]) ----
    #pragma unroll
    for (int i = 0; i < 32; ++i) {
        const int cell = i * 256 + t;
        const int row = cell & 127, c = cell >> 7;
        zs[row * 68 + c] = z[((b * 64 + c) << 10) + hw0 + row];
    }
    __syncthreads();

    // ---- per-row ||z||^2, sequential k ----
    if (t < 128) {
        const float4* z4 = (const float4*)zs + t * 17;
        float s = 0.f;
        #pragma unroll
        for (int g = 0; g < 16; ++g) {
            const float4 v = z4[g];
            s = fmaf(v.x, v.x, s); s = fmaf(v.y, v.y, s);
            s = fmaf(v.z, v.z, s); s = fmaf(v.w, v.w, s);
        }
        zn_s[t] = s;
    }
    __syncthreads();

    float znr[8];
    #pragma unroll
    for (int rr = 0; rr < 8; ++rr) znr[rr] = zn_s[ty + 16 * rr];

    float best[8]; int bidx[8];
    #pragma unroll
    for (int rr = 0; rr < 8; ++rr) { best[rr] = INFINITY; bidx[rr] = 0; }

    const float4* __restrict__ eg  = (const float4*)(emb + (half << 9) * 64);
    const float4* __restrict__ zs4 = (const float4*)zs;
    const float4* __restrict__ es4 = (const float4*)es;

    for (int ch = 0; ch < 4; ++ch) {
        const int cbase = (half << 9) + (ch << 7);
        // issue global loads early; they drain while waves sit at the barrier
        float4 pf[8];
        #pragma unroll
        for (int p = 0; p < 8; ++p) pf[p] = eg[ch * 2048 + p * 256 + t];
        float enj[8];
        #pragma unroll
        for (int j = 0; j < 8; ++j) enj[j] = enorm[cbase + tx + 16 * j];

        __syncthreads();           // previous chunk fully consumed
        #pragma unroll
        for (int p = 0; p < 8; ++p) {
            const int fid = p * 256 + t;
            ((float4*)es)[(fid >> 4) * 17 + (fid & 15)] = pf[p];
        }
        __syncthreads();

        // ---- software-pipelined 8x8 tile, K=64 as 16 float4 steps ----
        float acc[8][8];
        #pragma unroll
        for (int rr = 0; rr < 8; ++rr)
            #pragma unroll
            for (int j = 0; j < 8; ++j) acc[rr][j] = 0.f;

        float4 zf[8], efA[8], efB[8];
        ldfrag(efA, es4, tx, 0);
        #pragma unroll
        for (int gp = 0; gp < 8; ++gp) {
            ldfrag(zf, zs4, ty, 2 * gp);
            ldfrag(efB, es4, tx, 2 * gp + 1);
            fma_tile(zf, efA, acc);            // consumes g = 2gp
            ldfrag(zf, zs4, ty, 2 * gp + 1);   // SSA-renamed, no WAR stall
            if (gp < 7) ldfrag(efA, es4, tx, 2 * gp + 2);
            fma_tile(zf, efB, acc);            // consumes g = 2gp+1
        }

        // ---- scores + running argmin (codes ascending within thread) ----
        #pragma unroll
        for (int rr = 0; rr < 8; ++rr)
            #pragma unroll
            for (int j = 0; j < 8; ++j) {
                const float s = (znr[rr] + enj[j]) - 2.0f * acc[rr][j];
                if (s < best[rr]) { best[rr] = s; bidx[rr] = cbase + tx + 16 * j; }
            }
    }

    // ---- reduce across the 16 tx lanes (tie -> lower code index) ----
    #pragma unroll
    for (int off = 1; off < 16; off <<= 1) {
        #pragma unroll
        for (int rr = 0; rr < 8; ++rr) {
            const float os = __shfl_xor(best[rr], off);
            const int   oi = __shfl_xor(bidx[rr], off);
            if (os < best[rr] || (os == best[rr] && oi < bidx[rr])) {
                best[rr] = os; bidx[rr] = oi;
            }
        }
    }
    if (tx == 0) {
        #pragma unroll
        for (int rr = 0; rr < 8; ++rr) {
            const int gr = r0 + ty + 16 * rr;
            half_score[half * N_ROWS + gr] = best[rr];
            half_idx  [half * N_ROWS + gr] = bidx[rr];
        }
    }
}

// ---------------- kernel 3: resolve argmin across halves + counts/sums ----
// NSPLIT-privatized atomics: block adds into copy (blockIdx.x & 3).
__global__ __launch_bounds__(256) void vq_resolve(
        const float* __restrict__ z,
        const float* __restrict__ half_score, const int* __restrict__ half_idx,
        int* __restrict__ idx_out, float* __restrict__ counts,
        float* __restrict__ sums) {
    __shared__ float zs[128 * 65];
    __shared__ int   idx_sh[128];
    const int t   = threadIdx.x;
    const int r0  = blockIdx.x * 128;
    const int b   = r0 >> 10;
    const int hw0 = r0 & 1023;
    const int sp  = blockIdx.x & (NSPLIT - 1);

    #pragma unroll
    for (int i = 0; i < 32; ++i) {
        const int cell = i * 256 + t;
        const int row = cell & 127, c = cell >> 7;
        zs[row * 65 + c] = z[((b * 64 + c) << 10) + hw0 + row];
    }
    if (t < 128) {
        const int gr = r0 + t;
        const float s0 = half_score[gr], s1 = half_score[N_ROWS + gr];
        const int   i0 = half_idx[gr],   i1 = half_idx[N_ROWS + gr];
        const int   bi = (s1 < s0) ? i1 : i0;   // tie -> half 0 (lower codes)
        idx_out[gr] = bi;
        idx_sh[t] = bi;
        atomicAdd(&counts[sp * N_CODES + bi], 1.0f);
    }
    __syncthreads();

    const int lane = t & 63, sub = t >> 6;
    #pragma unroll
    for (int i = 0; i < 32; ++i) {
        const int row = i * 4 + sub;
        atomicAdd(&sums[sp * 65536 + idx_sh[row] * 64 + lane], zs[row * 65 + lane]);
    }
}

// ---------------- kernel 4: EMA update -> new_embed; counts out; loss=0 ----
__global__ void vq_ema(const float* __restrict__ counts, const float* __restrict__ sums,
                       const float* __restrict__ cs, const float* __restrict__ csum,
                       float* __restrict__ new_embed, float* __restrict__ out_counts,
                       float* __restrict__ out_loss) {
    const int g = blockIdx.x * 256 + threadIdx.x;   // 0 .. 65535
    const int c = g >> 6, d = g & 63;
    const float cnt = (counts[c] + counts[N_CODES + c])
                    + (counts[2 * N_CODES + c] + counts[3 * N_CODES + c]);
    const float ssum = (sums[g] + sums[65536 + g]) + (sums[131072 + g] + sums[196608 + g]);
    const float nsize = 0.99f * cs[c] + 0.01f * cnt;
    const float nsum  = 0.99f * csum[g] + 0.01f * ssum;
    new_embed[g] = nsum / (nsize + 1e-5f);
    if (d == 0) out_counts[c] = cnt;
    if (g == 0) out_loss[0] = 0.f;
}

// ---------------- kernel 5: gather z_q, straight-through, loss -------------
__global__ __launch_bounds__(256) void vq_gather(
        const float* __restrict__ z, const int* __restrict__ idx,
        const float* __restrict__ new_embed,
        float* __restrict__ out_zq, float* __restrict__ out_loss) {
    __shared__ float red[4];
    const int t  = threadIdx.x;
    const int r0 = blockIdx.x * 256;
    const int b  = r0 >> 10;
    const int hw = (r0 & 1023) + t;
    const int myidx = idx[r0 + t];

    const float4* __restrict__ er = (const float4*)(new_embed + (myidx << 6));
    float4 e4[16];
    #pragma unroll
    for (int i = 0; i < 16; ++i) e4[i] = er[i];

    float lsum = 0.f;
    #pragma unroll
    for (int c = 0; c < 64; ++c) {
        const float e  = ((const float*)e4)[c];
        const int  off = ((b * 64 + c) << 10) + hw;
        const float zv = z[off];
        const float diff = e - zv;                    // z_q - zp (fp32)
        out_zq[off] = zv + diff;                      // straight-through
        lsum = fmaf(diff, diff, lsum);
    }
    #pragma unroll
    for (int off = 32; off >= 1; off >>= 1) lsum += __shfl_down(lsum, off);
    if ((t & 63) == 0) red[t >> 6] = lsum;
    __syncthreads();
    if (t == 0) {
        const float s = red[0] + red[1] + red[2] + red[3];
        atomicAdd(out_loss, s * (0.25f / 2097152.0f));   // BETA/2^21 exact
    }
}

// ---------------------------------------------------------------------------
extern "C" void kernel_launch(void* const* d_in, const int* in_sizes, int n_in,
                              void* d_out, int out_size, void* d_ws, size_t ws_size,
                              hipStream_t stream) {
    const float* z    = (const float*)d_in[0];   // (32,64,32,32)
    const float* emb  = (const float*)d_in[1];   // (1024,64)
    const float* cs   = (const float*)d_in[2];   // (1024,)
    const float* csum = (const float*)d_in[3];   // (1024,64)
    float* out = (float*)d_out;

    // ws layout
    int*   idx        = (int*)d_ws;                        // 32768 ints
    float* counts     = (float*)d_ws + 32768;              // NSPLIT*1024
    float* sums       = counts + NSPLIT * N_CODES;         // NSPLIT*65536
    float* enorm      = sums + NSPLIT * 65536;             // 1024
    float* new_embed  = enorm + 1024;                      // 65536
    float* half_score = new_embed + 65536;                 // 2*32768
    int*   half_idx   = (int*)(half_score + 2 * 32768);    // 2*32768

    // zero the privatized atomic accumulators (counts + sums, contiguous)
    hipMemsetAsync(counts, 0, NSPLIT * (N_CODES + 65536) * sizeof(float), stream);

    vq_enorm<<<4, 256, 0, stream>>>(emb, enorm);
    vq_dist<<<dim3(256, 2), 256, 0, stream>>>(z, emb, enorm, half_score, half_idx);
    vq_resolve<<<256, 256, 0, stream>>>(z, half_score, half_idx, idx, counts, sums);
    vq_ema<<<256, 256, 0, stream>>>(counts, sums, cs, csum, new_embed,
                                    out + ZQ_ELEMS + 1,   // counts out
                                    out + ZQ_ELEMS);      // loss out
    vq_gather<<<128, 256, 0, stream>>>(z, idx, new_embed, out, out + ZQ_ELEMS);
}